// Round 5
// baseline (595.704 us; speedup 1.0000x reference)
//
#include <hip/hip_runtime.h>

constexpr float BN_EPS = 1e-5f;

// bf16 helpers (bit ops; RNE on pack)
__device__ inline float2 bf2x2(unsigned int v) {
    union { unsigned int i; float f; } a, b;
    a.i = v << 16;
    b.i = v & 0xFFFF0000u;
    return make_float2(a.f, b.f);
}
__device__ inline float4 bfu2(uint2 u) {
    float2 p = bf2x2(u.x), q = bf2x2(u.y);
    return make_float4(p.x, p.y, q.x, q.y);
}
__device__ inline unsigned short f2bf(float f) {
    union { float f; unsigned int i; } c;
    c.f = f;
    unsigned int i = c.i;
    return (unsigned short)((i + 0x7FFFu + ((i >> 16) & 1u)) >> 16);
}

// ---------------- init: zero deg counters + BN stat accumulators ----------------
__global__ void k_init(int* __restrict__ deg, float* __restrict__ stats, int n) {
    int i = blockIdx.x * blockDim.x + threadIdx.x;
    if (i < n) deg[i] = 0;
    if (blockIdx.x == 0 && threadIdx.x < 256) stats[threadIdx.x] = 0.f;
}

// ---------------- count in-degree over edges (excl self loops) ----------------
__global__ void k_count(const int* __restrict__ dst, int* __restrict__ deg, int E) {
    int i = blockIdx.x * blockDim.x + threadIdx.x;
    int stride = gridDim.x * blockDim.x;
    for (int e = i; e < E; e += stride) atomicAdd(&deg[dst[e]], 1);
}

// ---------------- hierarchical exclusive scan of deg -> rowptr (chunk = 1024) ----------------
__global__ __launch_bounds__(256) void k_blocksum(const int* __restrict__ deg, int* __restrict__ bsum, int n) {
    __shared__ int red[256];
    int b = blockIdx.x, tid = threadIdx.x;
    int i0 = b * 1024 + tid * 4;
    int s = 0;
#pragma unroll
    for (int k = 0; k < 4; ++k)
        if (i0 + k < n) s += deg[i0 + k];
    red[tid] = s;
    __syncthreads();
    for (int off = 128; off; off >>= 1) {
        if (tid < off) red[tid] += red[tid + off];
        __syncthreads();
    }
    if (tid == 0) bsum[b] = red[0];
}

__global__ __launch_bounds__(256) void k_scanbsums(const int* __restrict__ bsum, int* __restrict__ bofs, int nb) {
    __shared__ int tmp[256];
    int tid = threadIdx.x;
    int v = (tid < nb) ? bsum[tid] : 0;
    tmp[tid] = v;
    __syncthreads();
    for (int off = 1; off < 256; off <<= 1) {
        int t = (tid >= off) ? tmp[tid - off] : 0;
        __syncthreads();
        tmp[tid] += t;
        __syncthreads();
    }
    if (tid < nb) bofs[tid] = tmp[tid] - v;  // exclusive
}

__global__ __launch_bounds__(256) void k_scan_apply(const int* __restrict__ deg, const int* __restrict__ bofs,
                                                    int* __restrict__ rowptr, int* __restrict__ cursor,
                                                    float* __restrict__ dinv, int n) {
    __shared__ int tmp[256];
    int b = blockIdx.x, tid = threadIdx.x;
    int i0 = b * 1024 + tid * 4;
    int v[4];
#pragma unroll
    for (int k = 0; k < 4; ++k) v[k] = (i0 + k < n) ? deg[i0 + k] : 0;
    int tsum = v[0] + v[1] + v[2] + v[3];
    tmp[tid] = tsum;
    __syncthreads();
    for (int off = 1; off < 256; off <<= 1) {
        int t = (tid >= off) ? tmp[tid - off] : 0;
        __syncthreads();
        tmp[tid] += t;
        __syncthreads();
    }
    int p = tmp[tid] - tsum + bofs[b];
#pragma unroll
    for (int k = 0; k < 4; ++k) {
        if (i0 + k < n) {
            rowptr[i0 + k] = p;
            cursor[i0 + k] = p;
            dinv[i0 + k] = rsqrtf((float)(v[k] + 1));  // +1 self loop
        }
        p += v[k];
    }
}

// ---------------- permute: group src indices by dst (counting sort) ----------------
__global__ void k_permute(const int* __restrict__ src, const int* __restrict__ dst,
                          int* __restrict__ cursor, int* __restrict__ esrc, int E) {
    int i = blockIdx.x * blockDim.x + threadIdx.x;
    int stride = gridDim.x * blockDim.x;
    for (int e = i; e < E; e += stride) {
        int d = dst[e];
        int pos = atomicAdd(&cursor[d], 1);
        esrc[pos] = src[e];
    }
}

// ---------------- GEMM1: g1 = bf16( dinv ⊙ (x @ W1^T) ) ----------------
__global__ __launch_bounds__(256) void k_gemm1(const float* __restrict__ x,
                                               const float* __restrict__ W1,
                                               const float* __restrict__ dinv,
                                               unsigned short* __restrict__ g1, int n) {
    __shared__ float As[16][68];
    __shared__ float Bs[16][132];
    const int tid = threadIdx.x;
    const int row0 = blockIdx.x * 64;
    const int tx = tid & 31, ty = tid >> 5;
    float acc[8][4] = {};
    for (int k0 = 0; k0 < 128; k0 += 16) {
        {
            int r = tid >> 2;
            int kk4 = (tid & 3) * 4;
            int grow = row0 + r;
            float4 v = make_float4(0.f, 0.f, 0.f, 0.f);
            if (grow < n) v = *(const float4*)&x[(size_t)grow * 128 + k0 + kk4];
            As[kk4 + 0][r] = v.x; As[kk4 + 1][r] = v.y;
            As[kk4 + 2][r] = v.z; As[kk4 + 3][r] = v.w;
        }
        {
            int j = tid >> 1;
            int kb = (tid & 1) * 8;
            const float* wp = &W1[(size_t)j * 128 + k0 + kb];
            float4 v0 = *(const float4*)wp;
            float4 v1 = *(const float4*)(wp + 4);
            Bs[kb + 0][j] = v0.x; Bs[kb + 1][j] = v0.y; Bs[kb + 2][j] = v0.z; Bs[kb + 3][j] = v0.w;
            Bs[kb + 4][j] = v1.x; Bs[kb + 5][j] = v1.y; Bs[kb + 6][j] = v1.z; Bs[kb + 7][j] = v1.w;
        }
        __syncthreads();
#pragma unroll
        for (int kk = 0; kk < 16; ++kk) {
            float4 a0 = *(const float4*)&As[kk][ty * 8];
            float4 a1 = *(const float4*)&As[kk][ty * 8 + 4];
            float4 b  = *(const float4*)&Bs[kk][tx * 4];
            float a[8] = {a0.x, a0.y, a0.z, a0.w, a1.x, a1.y, a1.z, a1.w};
            float bb[4] = {b.x, b.y, b.z, b.w};
#pragma unroll
            for (int r = 0; r < 8; ++r)
#pragma unroll
                for (int c = 0; c < 4; ++c) acc[r][c] = fmaf(a[r], bb[c], acc[r][c]);
        }
        __syncthreads();
    }
#pragma unroll
    for (int r = 0; r < 8; ++r) {
        int grow = row0 + ty * 8 + r;
        if (grow < n) {
            float di = dinv[grow];
            ushort4 u;
            u.x = f2bf(acc[r][0] * di);
            u.y = f2bf(acc[r][1] * di);
            u.z = f2bf(acc[r][2] * di);
            u.w = f2bf(acc[r][3] * di);
            *(ushort4*)&g1[(size_t)grow * 128 + tx * 4] = u;
        }
    }
}

// ---------------- pull1: one node per HALF-WAVE (32 lanes x uint2 = 256B row) ----------------
// h1[d] = dinv[d]*(g1[d] + sum g1[src]) + b1 ; BN stats
__global__ __launch_bounds__(256) void k_pull1(const int* __restrict__ rowptr, const int* __restrict__ rowend,
                                               const int* __restrict__ esrc, const unsigned short* __restrict__ g,
                                               const float* __restrict__ dinv, const float* __restrict__ b1,
                                               float* __restrict__ h1, float* __restrict__ stats, int n) {
    __shared__ float4 sSum[8][32];
    __shared__ float4 sSq[8][32];
    const int tid = threadIdx.x;
    const int l = tid & 31;               // lane within half-wave: features l*4..l*4+3
    const int halfId = (tid >> 5) & 7;    // which half-wave in block (8 per 256-thread block)
    const int slot = blockIdx.x * 8 + (tid >> 5);
    const int nslots = gridDim.x * 8;
    const float4 bias = *(const float4*)&b1[l * 4];
    float4 psum = {0, 0, 0, 0}, psq = {0, 0, 0, 0};
    for (int node = slot; node < n; node += nslots) {
        const int b = rowptr[node], e = rowend[node];
        float4 a0 = bfu2(*(const uint2*)&g[(size_t)node * 128 + l * 4]);  // self loop
        float4 a1 = {0, 0, 0, 0}, a2 = {0, 0, 0, 0}, a3 = {0, 0, 0, 0};
        float4 a4 = {0, 0, 0, 0}, a5 = {0, 0, 0, 0}, a6 = {0, 0, 0, 0}, a7 = {0, 0, 0, 0};
        int j = b;
        for (; j + 8 <= e; j += 8) {
            int s0 = esrc[j + 0], s1 = esrc[j + 1], s2 = esrc[j + 2], s3 = esrc[j + 3];
            int s4 = esrc[j + 4], s5 = esrc[j + 5], s6 = esrc[j + 6], s7 = esrc[j + 7];
            uint2 v0 = *(const uint2*)&g[(size_t)s0 * 128 + l * 4];
            uint2 v1 = *(const uint2*)&g[(size_t)s1 * 128 + l * 4];
            uint2 v2 = *(const uint2*)&g[(size_t)s2 * 128 + l * 4];
            uint2 v3 = *(const uint2*)&g[(size_t)s3 * 128 + l * 4];
            uint2 v4 = *(const uint2*)&g[(size_t)s4 * 128 + l * 4];
            uint2 v5 = *(const uint2*)&g[(size_t)s5 * 128 + l * 4];
            uint2 v6 = *(const uint2*)&g[(size_t)s6 * 128 + l * 4];
            uint2 v7 = *(const uint2*)&g[(size_t)s7 * 128 + l * 4];
            float4 f0 = bfu2(v0), f1 = bfu2(v1), f2 = bfu2(v2), f3 = bfu2(v3);
            float4 f4 = bfu2(v4), f5 = bfu2(v5), f6 = bfu2(v6), f7 = bfu2(v7);
            a0.x += f0.x; a0.y += f0.y; a0.z += f0.z; a0.w += f0.w;
            a1.x += f1.x; a1.y += f1.y; a1.z += f1.z; a1.w += f1.w;
            a2.x += f2.x; a2.y += f2.y; a2.z += f2.z; a2.w += f2.w;
            a3.x += f3.x; a3.y += f3.y; a3.z += f3.z; a3.w += f3.w;
            a4.x += f4.x; a4.y += f4.y; a4.z += f4.z; a4.w += f4.w;
            a5.x += f5.x; a5.y += f5.y; a5.z += f5.z; a5.w += f5.w;
            a6.x += f6.x; a6.y += f6.y; a6.z += f6.z; a6.w += f6.w;
            a7.x += f7.x; a7.y += f7.y; a7.z += f7.z; a7.w += f7.w;
        }
        for (; j < e; ++j) {
            int s = esrc[j];
            float4 v = bfu2(*(const uint2*)&g[(size_t)s * 128 + l * 4]);
            a0.x += v.x; a0.y += v.y; a0.z += v.z; a0.w += v.w;
        }
        float4 acc;
        acc.x = ((a0.x + a1.x) + (a2.x + a3.x)) + ((a4.x + a5.x) + (a6.x + a7.x));
        acc.y = ((a0.y + a1.y) + (a2.y + a3.y)) + ((a4.y + a5.y) + (a6.y + a7.y));
        acc.z = ((a0.z + a1.z) + (a2.z + a3.z)) + ((a4.z + a5.z) + (a6.z + a7.z));
        acc.w = ((a0.w + a1.w) + (a2.w + a3.w)) + ((a4.w + a5.w) + (a6.w + a7.w));
        const float di = dinv[node];
        float4 hv;
        hv.x = fmaf(acc.x, di, bias.x);
        hv.y = fmaf(acc.y, di, bias.y);
        hv.z = fmaf(acc.z, di, bias.z);
        hv.w = fmaf(acc.w, di, bias.w);
        *(float4*)&h1[(size_t)node * 128 + l * 4] = hv;
        psum.x += hv.x; psum.y += hv.y; psum.z += hv.z; psum.w += hv.w;
        psq.x = fmaf(hv.x, hv.x, psq.x);
        psq.y = fmaf(hv.y, hv.y, psq.y);
        psq.z = fmaf(hv.z, hv.z, psq.z);
        psq.w = fmaf(hv.w, hv.w, psq.w);
    }
    sSum[halfId][l] = psum;
    sSq[halfId][l] = psq;
    __syncthreads();
    if (tid < 32) {
        float4 t = {0, 0, 0, 0};
#pragma unroll
        for (int h = 0; h < 8; ++h) {
            float4 v = sSum[h][tid];
            t.x += v.x; t.y += v.y; t.z += v.z; t.w += v.w;
        }
        atomicAdd(&stats[tid * 4 + 0], t.x);
        atomicAdd(&stats[tid * 4 + 1], t.y);
        atomicAdd(&stats[tid * 4 + 2], t.z);
        atomicAdd(&stats[tid * 4 + 3], t.w);
    } else if (tid < 64) {
        int q = tid - 32;
        float4 t = {0, 0, 0, 0};
#pragma unroll
        for (int h = 0; h < 8; ++h) {
            float4 v = sSq[h][q];
            t.x += v.x; t.y += v.y; t.z += v.z; t.w += v.w;
        }
        atomicAdd(&stats[128 + q * 4 + 0], t.x);
        atomicAdd(&stats[128 + q * 4 + 1], t.y);
        atomicAdd(&stats[128 + q * 4 + 2], t.z);
        atomicAdd(&stats[128 + q * 4 + 3], t.w);
    }
}

// ---------------- BN scale/shift from sums ----------------
__global__ void k_bnfinal(float* __restrict__ stats, const float* __restrict__ gamma,
                          const float* __restrict__ beta, int n) {
    int f = threadIdx.x;  // 128 threads
    float inv_n = 1.f / (float)n;
    float mean = stats[f] * inv_n;
    float var = stats[128 + f] * inv_n - mean * mean;
    float sc = gamma[f] * rsqrtf(var + BN_EPS);
    stats[256 + f] = sc;
    stats[384 + f] = fmaf(-mean, sc, beta[f]);
}

// ---------------- GEMM2: g2 = bf16( dinv ⊙ (relu(BN(h1)) @ W2^T) ) ----------------
__global__ __launch_bounds__(256) void k_gemm2(const float* __restrict__ h1,
                                               const float* __restrict__ W2,
                                               const float* __restrict__ dinv,
                                               const float* __restrict__ stats,
                                               unsigned short* __restrict__ g2, int n) {
    __shared__ float As[16][68];
    __shared__ float Bs[16][68];
    __shared__ float sSc[128], sSh[128];
    const int tid = threadIdx.x;
    if (tid < 128) {
        sSc[tid] = stats[256 + tid];
        sSh[tid] = stats[384 + tid];
    }
    const int row0 = blockIdx.x * 64;
    const int tx = tid & 15, ty = tid >> 4;
    float acc[4][4] = {};
    __syncthreads();
    for (int k0 = 0; k0 < 128; k0 += 16) {
        {
            int r = tid >> 2;
            int kk4 = (tid & 3) * 4;
            int grow = row0 + r;
            float4 v = make_float4(0.f, 0.f, 0.f, 0.f);
            if (grow < n) v = *(const float4*)&h1[(size_t)grow * 128 + k0 + kk4];
            int k = k0 + kk4;
            As[kk4 + 0][r] = fmaxf(fmaf(v.x, sSc[k + 0], sSh[k + 0]), 0.f);
            As[kk4 + 1][r] = fmaxf(fmaf(v.y, sSc[k + 1], sSh[k + 1]), 0.f);
            As[kk4 + 2][r] = fmaxf(fmaf(v.z, sSc[k + 2], sSh[k + 2]), 0.f);
            As[kk4 + 3][r] = fmaxf(fmaf(v.w, sSc[k + 3], sSh[k + 3]), 0.f);
        }
        {
            int j = tid >> 2;
            int kb = (tid & 3) * 4;
            float4 v = *(const float4*)&W2[(size_t)j * 128 + k0 + kb];
            Bs[kb + 0][j] = v.x; Bs[kb + 1][j] = v.y;
            Bs[kb + 2][j] = v.z; Bs[kb + 3][j] = v.w;
        }
        __syncthreads();
#pragma unroll
        for (int kk = 0; kk < 16; ++kk) {
            float4 a = *(const float4*)&As[kk][ty * 4];
            float4 b = *(const float4*)&Bs[kk][tx * 4];
            float aa[4] = {a.x, a.y, a.z, a.w};
            float bb[4] = {b.x, b.y, b.z, b.w};
#pragma unroll
            for (int r = 0; r < 4; ++r)
#pragma unroll
                for (int c = 0; c < 4; ++c) acc[r][c] = fmaf(aa[r], bb[c], acc[r][c]);
        }
        __syncthreads();
    }
#pragma unroll
    for (int r = 0; r < 4; ++r) {
        int grow = row0 + ty * 4 + r;
        if (grow < n) {
            float di = dinv[grow];
            ushort4 u;
            u.x = f2bf(acc[r][0] * di);
            u.y = f2bf(acc[r][1] * di);
            u.z = f2bf(acc[r][2] * di);
            u.w = f2bf(acc[r][3] * di);
            *(ushort4*)&g2[(size_t)grow * 64 + tx * 4] = u;
        }
    }
}

// ---------------- pull2: one node per QUARTER-WAVE (16 lanes x uint2 = 128B row) ----------------
// out[d] = dinv[d]*(g2[d] + sum g2[src]) + b2
__global__ __launch_bounds__(256) void k_pull2(const int* __restrict__ rowptr, const int* __restrict__ rowend,
                                               const int* __restrict__ esrc, const unsigned short* __restrict__ g,
                                               const float* __restrict__ dinv, const float* __restrict__ b2,
                                               float* __restrict__ out, int n) {
    const int tid = threadIdx.x;
    const int l = tid & 15;               // features l*4..l*4+3
    const int slot = blockIdx.x * 16 + (tid >> 4);
    const int nslots = gridDim.x * 16;
    const float4 bias = *(const float4*)&b2[l * 4];
    for (int node = slot; node < n; node += nslots) {
        const int b = rowptr[node], e = rowend[node];
        float4 a0 = bfu2(*(const uint2*)&g[(size_t)node * 64 + l * 4]);  // self loop
        float4 a1 = {0, 0, 0, 0}, a2 = {0, 0, 0, 0}, a3 = {0, 0, 0, 0};
        float4 a4 = {0, 0, 0, 0}, a5 = {0, 0, 0, 0}, a6 = {0, 0, 0, 0}, a7 = {0, 0, 0, 0};
        int j = b;
        for (; j + 8 <= e; j += 8) {
            int s0 = esrc[j + 0], s1 = esrc[j + 1], s2 = esrc[j + 2], s3 = esrc[j + 3];
            int s4 = esrc[j + 4], s5 = esrc[j + 5], s6 = esrc[j + 6], s7 = esrc[j + 7];
            uint2 v0 = *(const uint2*)&g[(size_t)s0 * 64 + l * 4];
            uint2 v1 = *(const uint2*)&g[(size_t)s1 * 64 + l * 4];
            uint2 v2 = *(const uint2*)&g[(size_t)s2 * 64 + l * 4];
            uint2 v3 = *(const uint2*)&g[(size_t)s3 * 64 + l * 4];
            uint2 v4 = *(const uint2*)&g[(size_t)s4 * 64 + l * 4];
            uint2 v5 = *(const uint2*)&g[(size_t)s5 * 64 + l * 4];
            uint2 v6 = *(const uint2*)&g[(size_t)s6 * 64 + l * 4];
            uint2 v7 = *(const uint2*)&g[(size_t)s7 * 64 + l * 4];
            float4 f0 = bfu2(v0), f1 = bfu2(v1), f2 = bfu2(v2), f3 = bfu2(v3);
            float4 f4 = bfu2(v4), f5 = bfu2(v5), f6 = bfu2(v6), f7 = bfu2(v7);
            a0.x += f0.x; a0.y += f0.y; a0.z += f0.z; a0.w += f0.w;
            a1.x += f1.x; a1.y += f1.y; a1.z += f1.z; a1.w += f1.w;
            a2.x += f2.x; a2.y += f2.y; a2.z += f2.z; a2.w += f2.w;
            a3.x += f3.x; a3.y += f3.y; a3.z += f3.z; a3.w += f3.w;
            a4.x += f4.x; a4.y += f4.y; a4.z += f4.z; a4.w += f4.w;
            a5.x += f5.x; a5.y += f5.y; a5.z += f5.z; a5.w += f5.w;
            a6.x += f6.x; a6.y += f6.y; a6.z += f6.z; a6.w += f6.w;
            a7.x += f7.x; a7.y += f7.y; a7.z += f7.z; a7.w += f7.w;
        }
        for (; j < e; ++j) {
            int s = esrc[j];
            float4 v = bfu2(*(const uint2*)&g[(size_t)s * 64 + l * 4]);
            a0.x += v.x; a0.y += v.y; a0.z += v.z; a0.w += v.w;
        }
        float4 acc;
        acc.x = ((a0.x + a1.x) + (a2.x + a3.x)) + ((a4.x + a5.x) + (a6.x + a7.x));
        acc.y = ((a0.y + a1.y) + (a2.y + a3.y)) + ((a4.y + a5.y) + (a6.y + a7.y));
        acc.z = ((a0.z + a1.z) + (a2.z + a3.z)) + ((a4.z + a5.z) + (a6.z + a7.z));
        acc.w = ((a0.w + a1.w) + (a2.w + a3.w)) + ((a4.w + a5.w) + (a6.w + a7.w));
        const float di = dinv[node];
        float4 o;
        o.x = fmaf(acc.x, di, bias.x);
        o.y = fmaf(acc.y, di, bias.y);
        o.z = fmaf(acc.z, di, bias.z);
        o.w = fmaf(acc.w, di, bias.w);
        *(float4*)&out[(size_t)node * 64 + l * 4] = o;
    }
}

extern "C" void kernel_launch(void* const* d_in, const int* in_sizes, int n_in,
                              void* d_out, int out_size, void* d_ws, size_t ws_size,
                              hipStream_t stream) {
    const float* x     = (const float*)d_in[0];
    const int*   ei    = (const int*)d_in[1];
    const float* W1    = (const float*)d_in[2];
    const float* b1    = (const float*)d_in[3];
    const float* gamma = (const float*)d_in[4];
    const float* beta  = (const float*)d_in[5];
    const float* W2    = (const float*)d_in[6];
    const float* b2    = (const float*)d_in[7];
    float* out = (float*)d_out;

    const int n = in_sizes[0] / 128;
    const int E = in_sizes[1] / 2;
    const int* src = ei;
    const int* dst = ei + E;

    char* ws = (char*)d_ws;
    const int Np = (n + 255) & ~255;
    const int Ep = (E + 3) & ~3;
    int*   deg    = (int*)ws;
    int*   rowptr = deg + Np;
    int*   cursor = rowptr + Np;
    float* dinv   = (float*)(cursor + Np);
    float* stats  = dinv + Np;
    int*   bsum   = (int*)(stats + 512);
    int*   bofs   = bsum + 1024;
    int*   esrc   = bofs + 1024;
    unsigned short* g1 = (unsigned short*)(esrc + Ep);     // n*128 bf16
    float* h1     = (float*)(g1 + (size_t)n * 128);        // n*128 f32
    unsigned short* g2 = g1;                               // reuse (g1 dead after pull1)

    const int nb = (n + 255) / 256;
    const int nscan = (n + 1023) / 1024;
    const int gb = (n + 63) / 64;

    hipLaunchKernelGGL(k_init, dim3(nb), dim3(256), 0, stream, deg, stats, n);
    hipLaunchKernelGGL(k_count, dim3(1024), dim3(256), 0, stream, dst, deg, E);
    hipLaunchKernelGGL(k_blocksum, dim3(nscan), dim3(256), 0, stream, deg, bsum, n);
    hipLaunchKernelGGL(k_scanbsums, dim3(1), dim3(256), 0, stream, bsum, bofs, nscan);
    hipLaunchKernelGGL(k_scan_apply, dim3(nscan), dim3(256), 0, stream, deg, bofs, rowptr, cursor, dinv, n);

    hipLaunchKernelGGL(k_gemm1, dim3(gb), dim3(256), 0, stream, x, W1, dinv, g1, n);
    hipLaunchKernelGGL(k_permute, dim3(1024), dim3(256), 0, stream, src, dst, cursor, esrc, E);
    hipLaunchKernelGGL(k_pull1, dim3(2048), dim3(256), 0, stream, rowptr, cursor, esrc, g1, dinv, b1, h1, stats, n);
    hipLaunchKernelGGL(k_bnfinal, dim3(1), dim3(128), 0, stream, stats, gamma, beta, n);

    hipLaunchKernelGGL(k_gemm2, dim3(gb), dim3(256), 0, stream, h1, W2, dinv, stats, g2, n);
    hipLaunchKernelGGL(k_pull2, dim3(2048), dim3(256), 0, stream, rowptr, cursor, esrc, g2, dinv, b2, out, n);
}